// Round 7
// baseline (167.894 us; speedup 1.0000x reference)
//
#include <hip/hip_runtime.h>
#include <math.h>

typedef unsigned short u16;
typedef unsigned int   u32;
typedef __attribute__((ext_vector_type(8))) _Float16 f16x8;
typedef __attribute__((ext_vector_type(4))) float f32x4;

#define DMODEL 768
#define SEQ    2048
#define BATCH  2
#define NHEAD  12
#define DKH    64
#define PER_BATCH (SEQ*DMODEL)
#define PER_HEAD  (SEQ*DKH)
#define ATT_SCALE 0.125f

__device__ inline u16 f2h(float f) {
    _Float16 h = (_Float16)f;           // v_cvt_f16_f32, RTNE
    return *(u16*)&h;
}
__device__ inline float4 h4f(uint2 v) {
    _Float16* p = (_Float16*)&v;
    return make_float4((float)p[0], (float)p[1], (float)p[2], (float)p[3]);
}

__device__ inline void async_load16(const void* g, void* l) {
    __builtin_amdgcn_global_load_lds(
        (const __attribute__((address_space(1))) unsigned int*)g,
        (__attribute__((address_space(3))) unsigned int*)l, 16, 0, 0);
}

// ---------------------------------------------------------------------------
// Conversion / prep, one launch. z=0: x->xh(fp16); z=1..3: Wq/Wk/Wv->Wh3;
// z=4: Wf->Wfh; z=5: bc = Wf@bo + bf; z=6: WoT = fp16(Wo^T); z=7: zero Mred.
// grid (576, 8).
// ---------------------------------------------------------------------------
__global__ void conv_all(const float* __restrict__ x,
                         const float* __restrict__ Wq, const float* __restrict__ Wk,
                         const float* __restrict__ Wv, const float* __restrict__ Wf,
                         const float* __restrict__ Wo,
                         const float* __restrict__ bo, const float* __restrict__ bfb,
                         u16* xh, u16* Wh3, u16* Wfh, u16* WoT, float* bc,
                         float* Mred)
{
    const int z = blockIdx.y;
    if (z == 5) {
        if (blockIdx.x >= 48) return;
        const int row    = blockIdx.x * 16 + (threadIdx.x >> 4);
        const int lane16 = threadIdx.x & 15;
        const float* r = Wf + (size_t)row * 768;
        float s = 0.f;
        #pragma unroll
        for (int t = 0; t < 48; ++t) s += r[lane16 + 16 * t] * bo[lane16 + 16 * t];
        #pragma unroll
        for (int off = 8; off > 0; off >>= 1) s += __shfl_xor(s, off, 64);
        if (lane16 == 0) bc[row] = s + bfb[row];
        return;
    }
    if (z == 6) {
        __shared__ u16 S[32][33];
        const int bi = blockIdx.x / 24, bj = blockIdx.x % 24;
        if (blockIdx.x >= 576) return;
        const int r  = threadIdx.x >> 3;
        const int c4 = threadIdx.x & 7;
        float4 v = *(const float4*)&Wo[(size_t)(bi * 32 + r) * 768 + bj * 32 + c4 * 4];
        S[c4 * 4 + 0][r] = f2h(v.x); S[c4 * 4 + 1][r] = f2h(v.y);
        S[c4 * 4 + 2][r] = f2h(v.z); S[c4 * 4 + 3][r] = f2h(v.w);
        __syncthreads();
        u16 o0 = S[r][c4 * 4 + 0], o1 = S[r][c4 * 4 + 1];
        u16 o2 = S[r][c4 * 4 + 2], o3 = S[r][c4 * 4 + 3];
        uint2 pk; pk.x = (u32)o0 | ((u32)o1 << 16); pk.y = (u32)o2 | ((u32)o3 << 16);
        *(uint2*)&WoT[(size_t)(bj * 32 + r) * 768 + bi * 32 + c4 * 4] = pk;
        return;
    }
    if (z == 7) {
        // zero Mred: 24*4096 floats = 24576 float4, 96 blocks x 256 thr x 1 f4
        if (blockIdx.x >= 96) return;
        ((float4*)Mred)[(size_t)blockIdx.x * 256 + threadIdx.x] =
            (float4){0.f, 0.f, 0.f, 0.f};
        return;
    }
    const float* src; u16* dst; int n;
    switch (z) {
        case 0: src = x;  dst = xh;            n = 3145728; break;
        case 1: src = Wq; dst = Wh3;           n = 589824;  break;
        case 2: src = Wk; dst = Wh3 + 589824;  n = 589824;  break;
        case 3: src = Wv; dst = Wh3 + 1179648; n = 589824;  break;
        default:src = Wf; dst = Wfh;           n = 589824;  break;
    }
    const int n4 = n >> 2;
    for (int i = blockIdx.x * blockDim.x + threadIdx.x; i < n4; i += gridDim.x * blockDim.x) {
        float4 v = ((const float4*)src)[i];
        u16 h0 = f2h(v.x), h1 = f2h(v.y), h2 = f2h(v.z), h3 = f2h(v.w);
        uint2 hp; hp.x = (u32)h0 | ((u32)h1 << 16); hp.y = (u32)h2 | ((u32)h3 << 16);
        ((uint2*)dst)[i] = hp;
    }
}

// ---------------------------------------------------------------------------
// QKV (+Wc) GEMM, fp16 MFMA, 128x128 tile, BK=64, grid (36,19).
//  by<18:  C = x @ {Wq,Wk,Wv}^T + bias -> Q (fp32), K (fp16), V (fp16)
//  by==18: Wc = Wf @ Wo  (A=Wfh, B=WoT, fp16 out, 36 tiles)
// XOR swizzle keeps stores/reads conflict-free.
// ---------------------------------------------------------------------------
__global__ __launch_bounds__(256, 3) void qkv_gemm(
    const u16* __restrict__ xh, const u16* __restrict__ Wh3,
    const u16* __restrict__ Wfh, const u16* __restrict__ WoT,
    const float* __restrict__ bq, const float* __restrict__ bk, const float* __restrict__ bv,
    float* __restrict__ Q, u16* __restrict__ Kh, u16* __restrict__ Vh,
    u16* __restrict__ Wcb)
{
    const int tid = threadIdx.x;
    const int w   = tid >> 6;
    const int L   = tid & 63;
    const int wr  = w >> 1, wc = w & 1;

    const u16 *Ap, *Bp;
    int mBase, nBaseB, mode;
    if (blockIdx.y == 18) {
        if (blockIdx.x >= 36) return;
        Ap = Wfh; Bp = WoT;
        mBase  = (blockIdx.x / 6) * 128;
        nBaseB = (blockIdx.x % 6) * 128;
        mode = 3;
    } else {
        if (blockIdx.x >= 32) return;
        Ap = xh; Bp = Wh3;
        mBase  = blockIdx.x * 128;
        nBaseB = blockIdx.y * 128;
        mode = nBaseB / 768;
    }

    __shared__ __align__(16) u16 As[128 * 64];
    __shared__ __align__(16) u16 Bs[128 * 64];

    f32x4 acc[4][4];
    #pragma unroll
    for (int i = 0; i < 4; ++i)
        #pragma unroll
        for (int j = 0; j < 4; ++j)
            acc[i][j] = (f32x4){0.f, 0.f, 0.f, 0.f};

    const int srow = L >> 3;
    const int kScr = ((L & 7) ^ (srow & 7)) * 8;
    const int rin = L & 15, q = L >> 4;

    for (int kb = 0; kb < 768; kb += 64) {
        if (kb) __syncthreads();
        #pragma unroll
        for (int cc = 0; cc < 2; ++cc) {
            const int ch = w * 2 + cc;
            const size_t rA = (size_t)(mBase + ch * 16 + srow) * 768 + kb + kScr;
            async_load16(&Ap[rA],           &As[ch * 1024]);
            async_load16(&Ap[rA + 8 * 768], &As[ch * 1024 + 512]);
            const size_t rB = (size_t)(nBaseB + ch * 16 + srow) * 768 + kb + kScr;
            async_load16(&Bp[rB],           &Bs[ch * 1024]);
            async_load16(&Bp[rB + 8 * 768], &Bs[ch * 1024 + 512]);
        }
        __syncthreads();

        #pragma unroll
        for (int kq = 0; kq < 2; ++kq) {
            const int slot = ((kq * 4 + q) ^ (rin & 7)) * 8;
            f16x8 af[4], bfr[4];
            #pragma unroll
            for (int i = 0; i < 4; ++i)
                af[i] = *(const f16x8*)&As[(wr * 64 + i * 16 + rin) * 64 + slot];
            #pragma unroll
            for (int j = 0; j < 4; ++j)
                bfr[j] = *(const f16x8*)&Bs[(wc * 64 + j * 16 + rin) * 64 + slot];
            #pragma unroll
            for (int i = 0; i < 4; ++i)
                #pragma unroll
                for (int j = 0; j < 4; ++j)
                    acc[i][j] = __builtin_amdgcn_mfma_f32_16x16x32_f16(af[i], bfr[j], acc[i][j], 0, 0, 0);
        }
    }

    const int nOff = (mode == 3) ? nBaseB : (nBaseB % 768);
    const float* bias = (mode == 0) ? bq : ((mode == 1) ? bk : ((mode == 2) ? bv : nullptr));
    u16* Ch = (mode == 1) ? Kh : ((mode == 2) ? Vh : Wcb);

    #pragma unroll
    for (int j = 0; j < 4; ++j) {
        const int c = nOff + wc * 64 + j * 16 + rin;
        const float bvl = bias ? bias[c] : 0.f;
        #pragma unroll
        for (int i = 0; i < 4; ++i) {
            const int r0 = mBase + wr * 64 + i * 16 + q * 4;
            #pragma unroll
            for (int reg = 0; reg < 4; ++reg) {
                const float v = acc[i][j][reg] + bvl;
                if (mode == 0) Q[(size_t)(r0 + reg) * 768 + c] = v;
                else           Ch[(size_t)(r0 + reg) * 768 + c] = f2h(v);
            }
        }
    }
}

// ---------------------------------------------------------------------------
// Generic fp16 MFMA GEMM: C = A @ B^T + bias.  Tile 64x128, BK=64. (final proj)
// ---------------------------------------------------------------------------
__global__ __launch_bounds__(256, 4) void gemm_f16(
    const u16* __restrict__ A, const u16* __restrict__ B,
    const float* __restrict__ bias, float* __restrict__ C)
{
    const int tid = threadIdx.x;
    const int w   = tid >> 6;
    const int L   = tid & 63;
    const int wr  = w >> 1, wc = w & 1;
    const int mBase = blockIdx.x * 64;
    const int nBase = blockIdx.y * 128;

    __shared__ __align__(16) u16 As[64 * 64];
    __shared__ __align__(16) u16 Bs[128 * 64];

    f32x4 acc[2][4];
    #pragma unroll
    for (int i = 0; i < 2; ++i)
        #pragma unroll
        for (int j = 0; j < 4; ++j)
            acc[i][j] = (f32x4){0.f, 0.f, 0.f, 0.f};

    const int srow = L >> 3;
    const int kScr = ((L & 7) ^ (srow & 7)) * 8;
    const int rin = L & 15, q = L >> 4;

    for (int kb = 0; kb < 768; kb += 64) {
        if (kb) __syncthreads();
        {
            const size_t rA = (size_t)(mBase + w * 16 + srow) * 768 + kb + kScr;
            async_load16(&A[rA],           &As[w * 1024]);
            async_load16(&A[rA + 8 * 768], &As[w * 1024 + 512]);
        }
        #pragma unroll
        for (int cc = 0; cc < 2; ++cc) {
            const int cB = w * 2 + cc;
            const size_t rB = (size_t)(nBase + cB * 16 + srow) * 768 + kb + kScr;
            async_load16(&B[rB],           &Bs[cB * 1024]);
            async_load16(&B[rB + 8 * 768], &Bs[cB * 1024 + 512]);
        }
        __syncthreads();

        #pragma unroll
        for (int kq = 0; kq < 2; ++kq) {
            const int slot = ((kq * 4 + q) ^ (rin & 7)) * 8;
            f16x8 af[2], bfr[4];
            #pragma unroll
            for (int i = 0; i < 2; ++i)
                af[i] = *(const f16x8*)&As[(wr * 2 + i) * 1024 + rin * 64 + slot];
            #pragma unroll
            for (int j = 0; j < 4; ++j)
                bfr[j] = *(const f16x8*)&Bs[(wc * 4 + j) * 1024 + rin * 64 + slot];
            #pragma unroll
            for (int i = 0; i < 2; ++i)
                #pragma unroll
                for (int j = 0; j < 4; ++j)
                    acc[i][j] = __builtin_amdgcn_mfma_f32_16x16x32_f16(af[i], bfr[j], acc[i][j], 0, 0, 0);
        }
    }

    #pragma unroll
    for (int j = 0; j < 4; ++j) {
        const int c = nBase + wc * 64 + j * 16 + rin;
        const float bvl = bias[c];
        #pragma unroll
        for (int i = 0; i < 2; ++i) {
            const int r0 = mBase + wr * 32 + i * 16 + q * 4;
            #pragma unroll
            for (int reg = 0; reg < 4; ++reg)
                C[(size_t)(r0 + reg) * 768 + c] = acc[i][j][reg] + bvl;
        }
    }
}

// ---------------------------------------------------------------------------
// Phase A: per (b,h), partial M = SCALE * K_h^T V_h over a 128-row t-chunk;
// fp16 K/V in, fp32 compute, atomicAdd into pre-zeroed Mred. grid (16,24).
// ---------------------------------------------------------------------------
__global__ __launch_bounds__(256, 2) void kv_outer(
    const u16* __restrict__ Kh, const u16* __restrict__ Vh,
    float* __restrict__ Mred)
{
    const int chunk = blockIdx.x;
    const int p     = blockIdx.y;
    const int b = p / NHEAD, h = p % NHEAD;
    const u16* Kb = Kh + (size_t)b * PER_BATCH + (size_t)h * PER_HEAD + (size_t)chunk * 128 * DKH;
    const u16* Vb = Vh + (size_t)b * PER_BATCH + (size_t)h * PER_HEAD + (size_t)chunk * 128 * DKH;

    __shared__ __align__(16) float Ks[32][64];
    __shared__ __align__(16) float Vs[32][64];

    const int tid = threadIdx.x;
    const int tx  = tid & 15;
    const int ty  = tid >> 4;

    float acc[4][4];
    #pragma unroll
    for (int i = 0; i < 4; ++i)
        #pragma unroll
        for (int j = 0; j < 4; ++j) acc[i][j] = 0.f;

    for (int t0 = 0; t0 < 128; t0 += 32) {
        if (t0) __syncthreads();
        #pragma unroll
        for (int r = 0; r < 2; ++r) {
            int idx = tid + 256 * r;
            int row = idx >> 4;
            int c4  = idx & 15;
            uint2 kp = *(const uint2*)&Kb[(size_t)(t0 + row) * DKH + c4 * 4];
            uint2 vp = *(const uint2*)&Vb[(size_t)(t0 + row) * DKH + c4 * 4];
            *(float4*)&Ks[row][c4 * 4] = h4f(kp);
            *(float4*)&Vs[row][c4 * 4] = h4f(vp);
        }
        __syncthreads();
        #pragma unroll
        for (int tt = 0; tt < 32; ++tt) {
            float4 ka = *(const float4*)&Ks[tt][ty * 4];
            float4 va = *(const float4*)&Vs[tt][tx * 4];
            float a[4] = {ka.x, ka.y, ka.z, ka.w};
            float v[4] = {va.x, va.y, va.z, va.w};
            #pragma unroll
            for (int i = 0; i < 4; ++i)
                #pragma unroll
                for (int j = 0; j < 4; ++j)
                    acc[i][j] += a[i] * v[j];
        }
    }

    float* Mo = Mred + (size_t)p * 4096;
    #pragma unroll
    for (int i = 0; i < 4; ++i)
        #pragma unroll
        for (int j = 0; j < 4; ++j)
            atomicAdd(&Mo[(ty * 4 + i) * 64 + tx * 4 + j], acc[i][j] * ATT_SCALE);
}

// ---------------------------------------------------------------------------
// Phase B: register-tiled T = Q@Mred + fused softmax (64x64 tile, one barrier).
// MH written as fp16.
// ---------------------------------------------------------------------------
__global__ __launch_bounds__(256, 2) void attn_gemm(
    const float* __restrict__ Qbuf, const float* __restrict__ Mred,
    u16* __restrict__ MH)
{
    const int chunk = blockIdx.x;
    const int p     = blockIdx.y;
    const int b = p / NHEAD, h = p % NHEAD;
    const float* Qb = Qbuf + (size_t)b * PER_BATCH + (size_t)h * PER_HEAD + (size_t)chunk * 64 * DKH;
    u16* MHb        = MH   + (size_t)b * PER_BATCH + (size_t)h * PER_HEAD + (size_t)chunk * 64 * DKH;

    __shared__ float QsT[64][65];
    __shared__ __align__(16) float SM[64][64];

    const int tid = threadIdx.x;

    const float4* M4 = (const float4*)(Mred + (size_t)p * 4096);
    float4* SM4 = (float4*)SM;
    #pragma unroll
    for (int r = 0; r < 4; ++r) {
        int e4 = tid + 256 * r;
        SM4[e4] = M4[e4];
        int row = e4 >> 4, c4 = e4 & 15;
        float4 v = *(const float4*)&Qb[(size_t)row * DKH + c4 * 4];
        QsT[c4 * 4 + 0][row] = v.x; QsT[c4 * 4 + 1][row] = v.y;
        QsT[c4 * 4 + 2][row] = v.z; QsT[c4 * 4 + 3][row] = v.w;
    }
    __syncthreads();

    const int tx = tid & 15;
    const int ty = tid >> 4;

    float acc[4][4];
    #pragma unroll
    for (int i = 0; i < 4; ++i)
        #pragma unroll
        for (int j = 0; j < 4; ++j) acc[i][j] = 0.f;

    #pragma unroll 4
    for (int k = 0; k < 64; ++k) {
        float4 bv = *(const float4*)&SM[k][tx * 4];
        float aa[4] = {QsT[k][ty * 4 + 0], QsT[k][ty * 4 + 1],
                       QsT[k][ty * 4 + 2], QsT[k][ty * 4 + 3]};
        float bb[4] = {bv.x, bv.y, bv.z, bv.w};
        #pragma unroll
        for (int i = 0; i < 4; ++i)
            #pragma unroll
            for (int j = 0; j < 4; ++j)
                acc[i][j] += aa[i] * bb[j];
    }

    #pragma unroll
    for (int i = 0; i < 4; ++i) {
        float m = fmaxf(fmaxf(acc[i][0], acc[i][1]), fmaxf(acc[i][2], acc[i][3]));
        #pragma unroll
        for (int off = 1; off < 16; off <<= 1)
            m = fmaxf(m, __shfl_xor(m, off, 64));
        float e0 = __expf(acc[i][0] - m), e1 = __expf(acc[i][1] - m);
        float e2 = __expf(acc[i][2] - m), e3 = __expf(acc[i][3] - m);
        float s = (e0 + e1) + (e2 + e3);
        #pragma unroll
        for (int off = 1; off < 16; off <<= 1)
            s += __shfl_xor(s, off, 64);
        float inv = 1.f / s;
        u16 o0 = f2h(e0 * inv), o1 = f2h(e1 * inv);
        u16 o2 = f2h(e2 * inv), o3 = f2h(e3 * inv);
        uint2 pk; pk.x = (u32)o0 | ((u32)o1 << 16); pk.y = (u32)o2 | ((u32)o3 << 16);
        const int row = ty * 4 + i;
        *(uint2*)&MHb[(size_t)row * DKH + tx * 4] = pk;
    }
}

// ---------------------------------------------------------------------------
extern "C" void kernel_launch(void* const* d_in, const int* in_sizes, int n_in,
                              void* d_out, int out_size, void* d_ws, size_t ws_size,
                              hipStream_t stream)
{
    const float* x  = (const float*)d_in[0];
    const float* Wq = (const float*)d_in[1];
    const float* bq = (const float*)d_in[2];
    const float* Wk = (const float*)d_in[3];
    const float* bk = (const float*)d_in[4];
    const float* Wv = (const float*)d_in[5];
    const float* bv = (const float*)d_in[6];
    const float* Wo = (const float*)d_in[7];
    const float* bo = (const float*)d_in[8];
    const float* Wf = (const float*)d_in[9];
    const float* bf = (const float*)d_in[10];
    float* out = (float*)d_out;

    // Workspace: floats Q(3.1M) Mred(98K) bc(1K);
    // u16: xh(3.1M) Wh3(1.77M) Wfh(0.59M) WoT(0.59M) Wcb(0.59M) Kh(3.1M) Vh(3.1M)
    // alias: MH -> xh (dead after qkv_gemm).
    float* ws_f = (float*)d_ws;
    float* Q   = ws_f;
    float* Mrd = ws_f + 3145728;
    float* bc  = ws_f + 3244032;
    u16* ub  = (u16*)(ws_f + 3245056);
    u16* xh  = ub;
    u16* Wh3 = ub + 3145728;
    u16* Wfh = Wh3 + 1769472;
    u16* WoT = Wfh + 589824;
    u16* Wcb = WoT + 589824;
    u16* Kh  = Wcb + 589824;
    u16* Vh  = Kh  + 3145728;
    u16* MH  = xh;

    dim3 blk(256);
    // casts + Wo transpose + bc + Mred zero, one launch
    conv_all<<<dim3(576, 8), blk, 0, stream>>>(x, Wq, Wk, Wv, Wf, Wo, bo, bf,
                                               xh, Wh3, Wfh, WoT, bc, Mrd);
    // QKV (Q fp32, K/V fp16) + Wc = Wf@Wo, one launch
    qkv_gemm<<<dim3(36, 19), blk, 0, stream>>>(xh, Wh3, Wfh, WoT, bq, bk, bv,
                                               Q, Kh, Vh, Wcb);
    // M = SCALE * K^T V, atomic partials into pre-zeroed Mred
    kv_outer<<<dim3(16, 24), blk, 0, stream>>>(Kh, Vh, Mrd);
    // Softmax rows -> MH (fp16)
    attn_gemm<<<dim3(32, 24), blk, 0, stream>>>(Q, Mrd, MH);
    // Fused output projection: out = MH @ Wc^T + bc (fp32 out)
    gemm_f16<<<dim3(64, 6), blk, 0, stream>>>(MH, Wcb, bc, out);
}

// Round 8
// 150.374 us; speedup vs baseline: 1.1165x; 1.1165x over previous
//
#include <hip/hip_runtime.h>
#include <math.h>

typedef unsigned short u16;
typedef unsigned int   u32;
typedef __attribute__((ext_vector_type(8))) _Float16 f16x8;
typedef __attribute__((ext_vector_type(4))) float f32x4;

#define DMODEL 768
#define SEQ    2048
#define BATCH  2
#define NHEAD  12
#define DKH    64
#define PER_BATCH (SEQ*DMODEL)
#define PER_HEAD  (SEQ*DKH)
#define ATT_SCALE 0.125f

__device__ inline u16 f2h(float f) {
    _Float16 h = (_Float16)f;           // v_cvt_f16_f32, RTNE
    return *(u16*)&h;
}
__device__ inline float4 h4f(uint2 v) {
    _Float16* p = (_Float16*)&v;
    return make_float4((float)p[0], (float)p[1], (float)p[2], (float)p[3]);
}

__device__ inline void async_load16(const void* g, void* l) {
    __builtin_amdgcn_global_load_lds(
        (const __attribute__((address_space(1))) unsigned int*)g,
        (__attribute__((address_space(3))) unsigned int*)l, 16, 0, 0);
}

// ---------------------------------------------------------------------------
// Conversion / prep, one launch. z=0: x->xh(fp16); z=1..3: Wq/Wk/Wv->Wh3;
// z=4: Wf->Wfh; z=5: bc = Wf@bo + bf; z=6: WoT = fp16(Wo^T). grid (576, 7).
// ---------------------------------------------------------------------------
__global__ void conv_all(const float* __restrict__ x,
                         const float* __restrict__ Wq, const float* __restrict__ Wk,
                         const float* __restrict__ Wv, const float* __restrict__ Wf,
                         const float* __restrict__ Wo,
                         const float* __restrict__ bo, const float* __restrict__ bfb,
                         u16* xh, u16* Wh3, u16* Wfh, u16* WoT, float* bc)
{
    const int z = blockIdx.y;
    if (z == 5) {
        if (blockIdx.x >= 48) return;
        const int row    = blockIdx.x * 16 + (threadIdx.x >> 4);
        const int lane16 = threadIdx.x & 15;
        const float* r = Wf + (size_t)row * 768;
        float s = 0.f;
        #pragma unroll
        for (int t = 0; t < 48; ++t) s += r[lane16 + 16 * t] * bo[lane16 + 16 * t];
        #pragma unroll
        for (int off = 8; off > 0; off >>= 1) s += __shfl_xor(s, off, 64);
        if (lane16 == 0) bc[row] = s + bfb[row];
        return;
    }
    if (z == 6) {
        __shared__ u16 S[32][33];
        const int bi = blockIdx.x / 24, bj = blockIdx.x % 24;
        const int r  = threadIdx.x >> 3;
        const int c4 = threadIdx.x & 7;
        float4 v = *(const float4*)&Wo[(size_t)(bi * 32 + r) * 768 + bj * 32 + c4 * 4];
        S[c4 * 4 + 0][r] = f2h(v.x); S[c4 * 4 + 1][r] = f2h(v.y);
        S[c4 * 4 + 2][r] = f2h(v.z); S[c4 * 4 + 3][r] = f2h(v.w);
        __syncthreads();
        u16 o0 = S[r][c4 * 4 + 0], o1 = S[r][c4 * 4 + 1];
        u16 o2 = S[r][c4 * 4 + 2], o3 = S[r][c4 * 4 + 3];
        uint2 pk; pk.x = (u32)o0 | ((u32)o1 << 16); pk.y = (u32)o2 | ((u32)o3 << 16);
        *(uint2*)&WoT[(size_t)(bj * 32 + r) * 768 + bi * 32 + c4 * 4] = pk;
        return;
    }
    const float* src; u16* dst; int n;
    switch (z) {
        case 0: src = x;  dst = xh;            n = 3145728; break;
        case 1: src = Wq; dst = Wh3;           n = 589824;  break;
        case 2: src = Wk; dst = Wh3 + 589824;  n = 589824;  break;
        case 3: src = Wv; dst = Wh3 + 1179648; n = 589824;  break;
        default:src = Wf; dst = Wfh;           n = 589824;  break;
    }
    const int n4 = n >> 2;
    for (int i = blockIdx.x * blockDim.x + threadIdx.x; i < n4; i += gridDim.x * blockDim.x) {
        float4 v = ((const float4*)src)[i];
        u16 h0 = f2h(v.x), h1 = f2h(v.y), h2 = f2h(v.z), h3 = f2h(v.w);
        uint2 hp; hp.x = (u32)h0 | ((u32)h1 << 16); hp.y = (u32)h2 | ((u32)h3 << 16);
        ((uint2*)dst)[i] = hp;
    }
}

// ---------------------------------------------------------------------------
// QKV (+Wc) GEMM, fp16 MFMA, 128x128 tile, BK=64, grid (36,19).
//  by<18:  C = x @ {Wq,Wk,Wv}^T + bias -> Q (fp32), K (fp16), V (fp16)
//  by==18: Wc = Wf @ Wo  (A=Wfh, B=WoT, fp16 out, 36 tiles)
// XOR swizzle keeps stores/reads conflict-free.
// ---------------------------------------------------------------------------
__global__ __launch_bounds__(256, 3) void qkv_gemm(
    const u16* __restrict__ xh, const u16* __restrict__ Wh3,
    const u16* __restrict__ Wfh, const u16* __restrict__ WoT,
    const float* __restrict__ bq, const float* __restrict__ bk, const float* __restrict__ bv,
    float* __restrict__ Q, u16* __restrict__ Kh, u16* __restrict__ Vh,
    u16* __restrict__ Wcb)
{
    const int tid = threadIdx.x;
    const int w   = tid >> 6;
    const int L   = tid & 63;
    const int wr  = w >> 1, wc = w & 1;

    const u16 *Ap, *Bp;
    int mBase, nBaseB, mode;
    if (blockIdx.y == 18) {
        if (blockIdx.x >= 36) return;
        Ap = Wfh; Bp = WoT;
        mBase  = (blockIdx.x / 6) * 128;
        nBaseB = (blockIdx.x % 6) * 128;
        mode = 3;
    } else {
        if (blockIdx.x >= 32) return;
        Ap = xh; Bp = Wh3;
        mBase  = blockIdx.x * 128;
        nBaseB = blockIdx.y * 128;
        mode = nBaseB / 768;
    }

    __shared__ __align__(16) u16 As[128 * 64];
    __shared__ __align__(16) u16 Bs[128 * 64];

    f32x4 acc[4][4];
    #pragma unroll
    for (int i = 0; i < 4; ++i)
        #pragma unroll
        for (int j = 0; j < 4; ++j)
            acc[i][j] = (f32x4){0.f, 0.f, 0.f, 0.f};

    const int srow = L >> 3;
    const int kScr = ((L & 7) ^ (srow & 7)) * 8;
    const int rin = L & 15, q = L >> 4;

    for (int kb = 0; kb < 768; kb += 64) {
        if (kb) __syncthreads();
        #pragma unroll
        for (int cc = 0; cc < 2; ++cc) {
            const int ch = w * 2 + cc;
            const size_t rA = (size_t)(mBase + ch * 16 + srow) * 768 + kb + kScr;
            async_load16(&Ap[rA],           &As[ch * 1024]);
            async_load16(&Ap[rA + 8 * 768], &As[ch * 1024 + 512]);
            const size_t rB = (size_t)(nBaseB + ch * 16 + srow) * 768 + kb + kScr;
            async_load16(&Bp[rB],           &Bs[ch * 1024]);
            async_load16(&Bp[rB + 8 * 768], &Bs[ch * 1024 + 512]);
        }
        __syncthreads();

        #pragma unroll
        for (int kq = 0; kq < 2; ++kq) {
            const int slot = ((kq * 4 + q) ^ (rin & 7)) * 8;
            f16x8 af[4], bfr[4];
            #pragma unroll
            for (int i = 0; i < 4; ++i)
                af[i] = *(const f16x8*)&As[(wr * 64 + i * 16 + rin) * 64 + slot];
            #pragma unroll
            for (int j = 0; j < 4; ++j)
                bfr[j] = *(const f16x8*)&Bs[(wc * 64 + j * 16 + rin) * 64 + slot];
            #pragma unroll
            for (int i = 0; i < 4; ++i)
                #pragma unroll
                for (int j = 0; j < 4; ++j)
                    acc[i][j] = __builtin_amdgcn_mfma_f32_16x16x32_f16(af[i], bfr[j], acc[i][j], 0, 0, 0);
        }
    }

    const int nOff = (mode == 3) ? nBaseB : (nBaseB % 768);
    const float* bias = (mode == 0) ? bq : ((mode == 1) ? bk : ((mode == 2) ? bv : nullptr));
    u16* Ch = (mode == 1) ? Kh : ((mode == 2) ? Vh : Wcb);

    #pragma unroll
    for (int j = 0; j < 4; ++j) {
        const int c = nOff + wc * 64 + j * 16 + rin;
        const float bvl = bias ? bias[c] : 0.f;
        #pragma unroll
        for (int i = 0; i < 4; ++i) {
            const int r0 = mBase + wr * 64 + i * 16 + q * 4;
            #pragma unroll
            for (int reg = 0; reg < 4; ++reg) {
                const float v = acc[i][j][reg] + bvl;
                if (mode == 0) Q[(size_t)(r0 + reg) * 768 + c] = v;
                else           Ch[(size_t)(r0 + reg) * 768 + c] = f2h(v);
            }
        }
    }
}

// ---------------------------------------------------------------------------
// Generic fp16 MFMA GEMM: C = A @ B^T + bias.  Tile 64x128, BK=64. (final proj)
// ---------------------------------------------------------------------------
__global__ __launch_bounds__(256, 4) void gemm_f16(
    const u16* __restrict__ A, const u16* __restrict__ B,
    const float* __restrict__ bias, float* __restrict__ C)
{
    const int tid = threadIdx.x;
    const int w   = tid >> 6;
    const int L   = tid & 63;
    const int wr  = w >> 1, wc = w & 1;
    const int mBase = blockIdx.x * 64;
    const int nBase = blockIdx.y * 128;

    __shared__ __align__(16) u16 As[64 * 64];
    __shared__ __align__(16) u16 Bs[128 * 64];

    f32x4 acc[2][4];
    #pragma unroll
    for (int i = 0; i < 2; ++i)
        #pragma unroll
        for (int j = 0; j < 4; ++j)
            acc[i][j] = (f32x4){0.f, 0.f, 0.f, 0.f};

    const int srow = L >> 3;
    const int kScr = ((L & 7) ^ (srow & 7)) * 8;
    const int rin = L & 15, q = L >> 4;

    for (int kb = 0; kb < 768; kb += 64) {
        if (kb) __syncthreads();
        {
            const size_t rA = (size_t)(mBase + w * 16 + srow) * 768 + kb + kScr;
            async_load16(&A[rA],           &As[w * 1024]);
            async_load16(&A[rA + 8 * 768], &As[w * 1024 + 512]);
        }
        #pragma unroll
        for (int cc = 0; cc < 2; ++cc) {
            const int cB = w * 2 + cc;
            const size_t rB = (size_t)(nBase + cB * 16 + srow) * 768 + kb + kScr;
            async_load16(&B[rB],           &Bs[cB * 1024]);
            async_load16(&B[rB + 8 * 768], &Bs[cB * 1024 + 512]);
        }
        __syncthreads();

        #pragma unroll
        for (int kq = 0; kq < 2; ++kq) {
            const int slot = ((kq * 4 + q) ^ (rin & 7)) * 8;
            f16x8 af[2], bfr[4];
            #pragma unroll
            for (int i = 0; i < 2; ++i)
                af[i] = *(const f16x8*)&As[(wr * 2 + i) * 1024 + rin * 64 + slot];
            #pragma unroll
            for (int j = 0; j < 4; ++j)
                bfr[j] = *(const f16x8*)&Bs[(wc * 4 + j) * 1024 + rin * 64 + slot];
            #pragma unroll
            for (int i = 0; i < 2; ++i)
                #pragma unroll
                for (int j = 0; j < 4; ++j)
                    acc[i][j] = __builtin_amdgcn_mfma_f32_16x16x32_f16(af[i], bfr[j], acc[i][j], 0, 0, 0);
        }
    }

    #pragma unroll
    for (int j = 0; j < 4; ++j) {
        const int c = nBase + wc * 64 + j * 16 + rin;
        const float bvl = bias[c];
        #pragma unroll
        for (int i = 0; i < 2; ++i) {
            const int r0 = mBase + wr * 32 + i * 16 + q * 4;
            #pragma unroll
            for (int reg = 0; reg < 4; ++reg)
                C[(size_t)(r0 + reg) * 768 + c] = acc[i][j][reg] + bvl;
        }
    }
}

// ---------------------------------------------------------------------------
// Phase A: per (b,h), partial M = K_h^T V_h over a 128-row t-chunk.
// fp16 K/V in, fp32 compute, fp32 partials to Mpart (no atomics). grid (16,24).
// ---------------------------------------------------------------------------
__global__ __launch_bounds__(256, 2) void kv_outer(
    const u16* __restrict__ Kh, const u16* __restrict__ Vh,
    float* __restrict__ Mpart)
{
    const int chunk = blockIdx.x;
    const int p     = blockIdx.y;
    const int b = p / NHEAD, h = p % NHEAD;
    const u16* Kb = Kh + (size_t)b * PER_BATCH + (size_t)h * PER_HEAD + (size_t)chunk * 128 * DKH;
    const u16* Vb = Vh + (size_t)b * PER_BATCH + (size_t)h * PER_HEAD + (size_t)chunk * 128 * DKH;

    __shared__ __align__(16) float Ks[32][64];
    __shared__ __align__(16) float Vs[32][64];

    const int tid = threadIdx.x;
    const int tx  = tid & 15;
    const int ty  = tid >> 4;

    float acc[4][4];
    #pragma unroll
    for (int i = 0; i < 4; ++i)
        #pragma unroll
        for (int j = 0; j < 4; ++j) acc[i][j] = 0.f;

    for (int t0 = 0; t0 < 128; t0 += 32) {
        if (t0) __syncthreads();
        #pragma unroll
        for (int r = 0; r < 2; ++r) {
            int idx = tid + 256 * r;
            int row = idx >> 4;
            int c4  = idx & 15;
            uint2 kp = *(const uint2*)&Kb[(size_t)(t0 + row) * DKH + c4 * 4];
            uint2 vp = *(const uint2*)&Vb[(size_t)(t0 + row) * DKH + c4 * 4];
            *(float4*)&Ks[row][c4 * 4] = h4f(kp);
            *(float4*)&Vs[row][c4 * 4] = h4f(vp);
        }
        __syncthreads();
        #pragma unroll
        for (int tt = 0; tt < 32; ++tt) {
            float4 ka = *(const float4*)&Ks[tt][ty * 4];
            float4 va = *(const float4*)&Vs[tt][tx * 4];
            float a[4] = {ka.x, ka.y, ka.z, ka.w};
            float v[4] = {va.x, va.y, va.z, va.w};
            #pragma unroll
            for (int i = 0; i < 4; ++i)
                #pragma unroll
                for (int j = 0; j < 4; ++j)
                    acc[i][j] += a[i] * v[j];
        }
    }

    float* Mo = Mpart + ((size_t)p * 16 + chunk) * 4096;
    #pragma unroll
    for (int i = 0; i < 4; ++i)
        #pragma unroll
        for (int j = 0; j < 4; ++j)
            Mo[(ty * 4 + i) * 64 + tx * 4 + j] = acc[i][j];
}

// ---------------------------------------------------------------------------
// Reduce the 16 chunk-partials of M, pre-scaled. grid (24, 4).
// ---------------------------------------------------------------------------
__global__ __launch_bounds__(256, 2) void reduce_M(
    const float* __restrict__ Mpart, float* __restrict__ Mred)
{
    const int p = blockIdx.x;
    const int e4 = blockIdx.y * 256 + threadIdx.x;
    const float4* Mp4 = (const float4*)Mpart + (size_t)p * 16384;
    float4 s = Mp4[e4];
    #pragma unroll
    for (int c = 1; c < 16; ++c) {
        float4 t = Mp4[(size_t)c * 1024 + e4];
        s.x += t.x; s.y += t.y; s.z += t.z; s.w += t.w;
    }
    s.x *= ATT_SCALE; s.y *= ATT_SCALE; s.z *= ATT_SCALE; s.w *= ATT_SCALE;
    ((float4*)Mred)[(size_t)p * 1024 + e4] = s;
}

// ---------------------------------------------------------------------------
// Phase B: register-tiled T = Q@Mred + fused softmax (64x64 tile, one barrier).
// MH written as fp16.
// ---------------------------------------------------------------------------
__global__ __launch_bounds__(256, 2) void attn_gemm(
    const float* __restrict__ Qbuf, const float* __restrict__ Mred,
    u16* __restrict__ MH)
{
    const int chunk = blockIdx.x;
    const int p     = blockIdx.y;
    const int b = p / NHEAD, h = p % NHEAD;
    const float* Qb = Qbuf + (size_t)b * PER_BATCH + (size_t)h * PER_HEAD + (size_t)chunk * 64 * DKH;
    u16* MHb        = MH   + (size_t)b * PER_BATCH + (size_t)h * PER_HEAD + (size_t)chunk * 64 * DKH;

    __shared__ float QsT[64][65];
    __shared__ __align__(16) float SM[64][64];

    const int tid = threadIdx.x;

    const float4* M4 = (const float4*)(Mred + (size_t)p * 4096);
    float4* SM4 = (float4*)SM;
    #pragma unroll
    for (int r = 0; r < 4; ++r) {
        int e4 = tid + 256 * r;
        SM4[e4] = M4[e4];
        int row = e4 >> 4, c4 = e4 & 15;
        float4 v = *(const float4*)&Qb[(size_t)row * DKH + c4 * 4];
        QsT[c4 * 4 + 0][row] = v.x; QsT[c4 * 4 + 1][row] = v.y;
        QsT[c4 * 4 + 2][row] = v.z; QsT[c4 * 4 + 3][row] = v.w;
    }
    __syncthreads();

    const int tx = tid & 15;
    const int ty = tid >> 4;

    float acc[4][4];
    #pragma unroll
    for (int i = 0; i < 4; ++i)
        #pragma unroll
        for (int j = 0; j < 4; ++j) acc[i][j] = 0.f;

    #pragma unroll 4
    for (int k = 0; k < 64; ++k) {
        float4 bv = *(const float4*)&SM[k][tx * 4];
        float aa[4] = {QsT[k][ty * 4 + 0], QsT[k][ty * 4 + 1],
                       QsT[k][ty * 4 + 2], QsT[k][ty * 4 + 3]};
        float bb[4] = {bv.x, bv.y, bv.z, bv.w};
        #pragma unroll
        for (int i = 0; i < 4; ++i)
            #pragma unroll
            for (int j = 0; j < 4; ++j)
                acc[i][j] += aa[i] * bb[j];
    }

    #pragma unroll
    for (int i = 0; i < 4; ++i) {
        float m = fmaxf(fmaxf(acc[i][0], acc[i][1]), fmaxf(acc[i][2], acc[i][3]));
        #pragma unroll
        for (int off = 1; off < 16; off <<= 1)
            m = fmaxf(m, __shfl_xor(m, off, 64));
        float e0 = __expf(acc[i][0] - m), e1 = __expf(acc[i][1] - m);
        float e2 = __expf(acc[i][2] - m), e3 = __expf(acc[i][3] - m);
        float s = (e0 + e1) + (e2 + e3);
        #pragma unroll
        for (int off = 1; off < 16; off <<= 1)
            s += __shfl_xor(s, off, 64);
        float inv = 1.f / s;
        u16 o0 = f2h(e0 * inv), o1 = f2h(e1 * inv);
        u16 o2 = f2h(e2 * inv), o3 = f2h(e3 * inv);
        uint2 pk; pk.x = (u32)o0 | ((u32)o1 << 16); pk.y = (u32)o2 | ((u32)o3 << 16);
        const int row = ty * 4 + i;
        *(uint2*)&MHb[(size_t)row * DKH + tx * 4] = pk;
    }
}

// ---------------------------------------------------------------------------
extern "C" void kernel_launch(void* const* d_in, const int* in_sizes, int n_in,
                              void* d_out, int out_size, void* d_ws, size_t ws_size,
                              hipStream_t stream)
{
    const float* x  = (const float*)d_in[0];
    const float* Wq = (const float*)d_in[1];
    const float* bq = (const float*)d_in[2];
    const float* Wk = (const float*)d_in[3];
    const float* bk = (const float*)d_in[4];
    const float* Wv = (const float*)d_in[5];
    const float* bv = (const float*)d_in[6];
    const float* Wo = (const float*)d_in[7];
    const float* bo = (const float*)d_in[8];
    const float* Wf = (const float*)d_in[9];
    const float* bf = (const float*)d_in[10];
    float* out = (float*)d_out;

    // Workspace (floats): Q(3.1M) Mpart(1.57M) Mred(98K) bc(1K)
    // u16: xh(3.1M) Wh3(1.77M) Wfh(0.59M) WoT(0.59M) Wcb(0.59M) Kh(3.1M) Vh(3.1M)
    // alias: MH -> xh (dead after qkv_gemm).
    float* ws_f = (float*)d_ws;
    float* Q   = ws_f;
    float* Mp  = ws_f + 3145728;
    float* Mrd = ws_f + 4718592;
    float* bc  = ws_f + 4816896;
    u16* ub  = (u16*)(ws_f + 4817920);
    u16* xh  = ub;
    u16* Wh3 = ub + 3145728;
    u16* Wfh = Wh3 + 1769472;
    u16* WoT = Wfh + 589824;
    u16* Wcb = WoT + 589824;
    u16* Kh  = Wcb + 589824;
    u16* Vh  = Kh  + 3145728;
    u16* MH  = xh;

    dim3 blk(256);
    // casts + Wo transpose + bc, one launch
    conv_all<<<dim3(576, 7), blk, 0, stream>>>(x, Wq, Wk, Wv, Wf, Wo, bo, bf,
                                               xh, Wh3, Wfh, WoT, bc);
    // QKV (Q fp32, K/V fp16) + Wc = Wf@Wo, one launch
    qkv_gemm<<<dim3(36, 19), blk, 0, stream>>>(xh, Wh3, Wfh, WoT, bq, bk, bv,
                                               Q, Kh, Vh, Wcb);
    // M partials (fp16 in, fp32 out), then scaled reduction
    kv_outer<<<dim3(16, 24), blk, 0, stream>>>(Kh, Vh, Mp);
    reduce_M<<<dim3(24, 4), blk, 0, stream>>>(Mp, Mrd);
    // Softmax rows -> MH (fp16)
    attn_gemm<<<dim3(32, 24), blk, 0, stream>>>(Q, Mrd, MH);
    // Fused output projection: out = MH @ Wc^T + bc (fp32 out)
    gemm_f16<<<dim3(64, 6), blk, 0, stream>>>(MH, Wcb, bc, out);
}